// Round 14
// baseline (175.550 us; speedup 1.0000x reference)
//
#include <hip/hip_runtime.h>
#include <math.h>

#define HEADS 16
#define DH    64
#define SEQ   2048
#define HID   1024
#define NROW  4096

typedef __attribute__((ext_vector_type(8))) short bf16x8;
typedef __attribute__((ext_vector_type(4))) short bf16x4;
typedef __attribute__((ext_vector_type(4))) float f32x4;

#define AS1 __attribute__((address_space(1)))
#define AS3 __attribute__((address_space(3)))

// 0.125 * log2(e): folds softmax scale and exp->exp2 into the Q pack.
#define QSCALE 0.18033688011112042f

__device__ __forceinline__ unsigned short f2bf(float x) {
    unsigned int u = __builtin_bit_cast(unsigned int, x);
    u = (u + 0x7FFFu + ((u >> 16) & 1u)) >> 16;
    return (unsigned short)u;
}

__device__ __forceinline__ void gload_lds16(const unsigned short* g, unsigned short* l) {
    __builtin_amdgcn_global_load_lds((AS1 void*)g, (AS3 void*)l, 16, 0, 0);
}

// ================= prep: conv_x + rope_tab + 2x wtrans in ONE launch =================
__device__ void wtrans_body(const float* __restrict__ wsrc, unsigned short* __restrict__ wt,
                            int K, int N, int bx, int by, float (*T)[65])
{
    const int tid = threadIdx.x;
    const int k0 = by * 64, n0 = bx * 64;
    #pragma unroll
    for (int rnd = 0; rnd < 4; ++rnd) {
        int row = (tid >> 4) + rnd * 16;
        int c = (tid & 15) * 4;
        float4 v = *(const float4*)&wsrc[(size_t)(k0 + row) * N + n0 + c];
        T[row][c] = v.x; T[row][c+1] = v.y; T[row][c+2] = v.z; T[row][c+3] = v.w;
    }
    __syncthreads();
    const int sr = tid >> 3, sc = (tid & 7) << 3;
    #pragma unroll
    for (int half = 0; half < 2; ++half) {
        int n = sr + half * 32;
        union { unsigned short u[8]; bf16x8 v; } pk;
        #pragma unroll
        for (int j = 0; j < 8; ++j) pk.u[j] = f2bf(T[sc + j][n]);
        *(bf16x8*)&wt[(size_t)(n0 + n) * K + k0 + sc] = pk.v;
    }
}

__global__ __launch_bounds__(256) void prep(const float* __restrict__ x,
                                            const float* __restrict__ rot,
                                            const float* __restrict__ w_qkv,
                                            const float* __restrict__ w_out,
                                            unsigned short* __restrict__ xb,
                                            float2* __restrict__ ctab,
                                            unsigned short* __restrict__ wqkvT,
                                            unsigned short* __restrict__ woutT)
{
    __shared__ float T[64][65];
    const int bid = blockIdx.x;
    if (bid < 2048) {
        size_t i = ((size_t)bid * 256 + threadIdx.x) * 8;
        float4 a = *(const float4*)&x[i];
        float4 b = *(const float4*)&x[i + 4];
        union { unsigned short u[8]; bf16x8 v; } pk;
        pk.u[0] = f2bf(a.x); pk.u[1] = f2bf(a.y); pk.u[2] = f2bf(a.z); pk.u[3] = f2bf(a.w);
        pk.u[4] = f2bf(b.x); pk.u[5] = f2bf(b.y); pk.u[6] = f2bf(b.z); pk.u[7] = f2bf(b.w);
        *(bf16x8*)&xb[i] = pk.v;
    } else if (bid < 2560) {
        int i = (bid - 2048) * 256 + threadIdx.x;   // SEQ*DH = 131072
        float r = rot[i];
        float s, c;
        __sincosf(r, &s, &c);
        ctab[i] = make_float2(c, s);
    } else if (bid < 3328) {
        int idx = bid - 2560;                       // 48 x 16
        wtrans_body(w_qkv, wqkvT, 1024, 3072, idx % 48, idx / 48, T);
    } else {
        int idx = bid - 3328;                       // 16 x 16
        wtrans_body(w_out, woutT, 1024, 1024, idx % 16, idx / 16, T);
    }
}

// ========== QKV GEMM v6: 128x128 tile, 2x2 wave grid (64x64/wave) — r10 proven ==========
// V written TILED+SWIZZLED: vt[bh][t][d][ks'] with ks' = ((ks>>2) ^ (d&7))<<2.
__global__ __launch_bounds__(256, 3) void gemm_qkv(const unsigned short* __restrict__ A,
                                                   const unsigned short* __restrict__ Bt,
                                                   const float2* __restrict__ ctab,
                                                   unsigned short* __restrict__ qb,
                                                   unsigned short* __restrict__ kb,
                                                   unsigned short* __restrict__ vt)
{
    __shared__ __align__(16) unsigned short As[128 * 64];   // 16 KB, chunk-XOR swizzled
    __shared__ __align__(16) unsigned short Bs[128 * 64];   // 16 KB
    const int tid = threadIdx.x;
    const int w = tid >> 6, lane = tid & 63;
    const int quad = lane >> 4, lm = lane & 15;
    const int wrow = (w >> 1) * 64, wcol = (w & 1) * 64;
    const int bm = blockIdx.y * 128, bn = blockIdx.x * 128;

    // staging constants: each gload line covers 32 rows x 64 cols (8 rows/wave)
    const int ga = w * 8 + (lane >> 3);                     // row within 32-row group
    const int gp = ((lane & 7) ^ (lane >> 3)) << 3;         // pre-swizzled source chunk

    // fragment read chunk offsets for the two K=32 halves
    int cko[2];
    #pragma unroll
    for (int c = 0; c < 2; ++c)
        cko[c] = (((c * 4 + quad) ^ (lm & 7)) << 3);

    f32x4 acc[4][4];
    #pragma unroll
    for (int i = 0; i < 4; ++i)
        #pragma unroll
        for (int j = 0; j < 4; ++j) acc[i][j] = (f32x4){0.f, 0.f, 0.f, 0.f};

    for (int k0 = 0; k0 < 1024; k0 += 64) {
        __syncthreads();
        #pragma unroll
        for (int i = 0; i < 4; ++i)
            gload_lds16(&A [(size_t)(bm + i * 32 + ga) * 1024 + k0 + gp], As + i * 2048 + w * 512);
        #pragma unroll
        for (int i = 0; i < 4; ++i)
            gload_lds16(&Bt[(size_t)(bn + i * 32 + ga) * 1024 + k0 + gp], Bs + i * 2048 + w * 512);
        __syncthreads();
        bf16x8 af[4][2], bfr[4][2];
        #pragma unroll
        for (int mt = 0; mt < 4; ++mt)
            #pragma unroll
            for (int c = 0; c < 2; ++c)
                af[mt][c] = *(const bf16x8*)&As[(wrow + mt * 16 + lm) * 64 + cko[c]];
        #pragma unroll
        for (int nt = 0; nt < 4; ++nt)
            #pragma unroll
            for (int c = 0; c < 2; ++c)
                bfr[nt][c] = *(const bf16x8*)&Bs[(wcol + nt * 16 + lm) * 64 + cko[c]];
        #pragma unroll
        for (int mt = 0; mt < 4; ++mt)
            #pragma unroll
            for (int nt = 0; nt < 4; ++nt) {
                acc[mt][nt] = __builtin_amdgcn_mfma_f32_16x16x32_bf16(af[mt][0], bfr[nt][0], acc[mt][nt], 0, 0, 0);
                acc[mt][nt] = __builtin_amdgcn_mfma_f32_16x16x32_bf16(af[mt][1], bfr[nt][1], acc[mt][nt], 0, 0, 0);
            }
    }

    const int colbase = bn + wcol;         // wave's 64-col slice = one (region, head)
    const int region = colbase >> 10;      // 0=q, 1=k, 2=v
    const int h = (colbase >> 6) & 15;

    if (region == 2) {
        #pragma unroll
        for (int mt = 0; mt < 4; ++mt) {
            int rowb = bm + wrow + mt * 16 + quad * 4;
            int b = rowb >> 11, seq = rowb & (SEQ - 1);
            int t = seq >> 5, ks = seq & 31;            // ks is a multiple of 4
            #pragma unroll
            for (int nt = 0; nt < 4; ++nt) {
                int d = nt * 16 + lm;
                int ksw = (((ks >> 2) ^ (lm & 7)) << 2);   // slot-level XOR swizzle
                ushort4 pk;
                pk.x = f2bf(acc[mt][nt][0]); pk.y = f2bf(acc[mt][nt][1]);
                pk.z = f2bf(acc[mt][nt][2]); pk.w = f2bf(acc[mt][nt][3]);
                *(ushort4*)&vt[(((size_t)(b * HEADS + h) * 64 + t) * 64 + d) * 32 + ksw] = pk;
            }
        }
    } else {
        const float qs = (region == 0) ? QSCALE : 1.0f;
        unsigned short* dst = (region == 0) ? qb : kb;
        #pragma unroll
        for (int mt = 0; mt < 4; ++mt) {
            #pragma unroll
            for (int nt = 0; nt < 2; ++nt) {
                int d = nt * 16 + lm;
                #pragma unroll
                for (int r = 0; r < 4; ++r) {
                    int row = bm + wrow + mt * 16 + quad * 4 + r;
                    int b = row >> 11, seq = row & (SEQ - 1);
                    float2 cs0 = ctab[seq * DH + d];
                    float2 cs1 = ctab[seq * DH + d + 32];
                    float x0 = acc[mt][nt][r];
                    float x1 = acc[mt][nt + 2][r];
                    size_t ob = ((size_t)(b * HEADS + h) * SEQ + seq) * DH;
                    dst[ob + d]      = f2bf((x0 * cs0.x - x1 * cs0.y) * qs);
                    dst[ob + d + 32] = f2bf((x1 * cs1.x + x0 * cs1.y) * qs);
                }
            }
        }
    }
}

// ========== Flash attention v13 (r10 proven: exp2 + scalar rs, exact fp32 denominator) ==========
// r11/r12 lesson (pre-committed): MFMA-rowsum with bf16 P in the denominator fails
// numerics (7e-3 / NaN) — the denominator stays on the exp2 + scalar-add + shfl path.
__global__ __launch_bounds__(256, 4) void attn13(const unsigned short* __restrict__ qb,
                                                 const unsigned short* __restrict__ kb,
                                                 const unsigned short* __restrict__ vt,
                                                 unsigned short* __restrict__ attnb)
{
    __shared__ __align__(16) char smem[32768];
    unsigned short* Ks = (unsigned short*)smem;             // [2 buf][64 kseq][64 d] swizzled rows
    unsigned short* Vs = (unsigned short*)(smem + 16384);   // [2 buf][2 t][64 d][32 ks'] slot-swizzled

    const int tid = threadIdx.x;
    const int w = tid >> 6, lane = tid & 63, quad = lane >> 4, lm = lane & 15;
    const int qg = w >> 1, kg = w & 1;

    // XCD-aware remap: all 32 q-tiles of one bh land on one XCD (linear L = x + 32y).
    // Per-XCD K/V working set = 4 bh x 512 KB = 2 MB < 4 MB L2.
    const int L = blockIdx.x + blockIdx.y * 32;
    const int bh = (L & 7) + 8 * ((L >> 3) & 3);
    const int q0 = (L >> 5) * 64;

    const int b = bh >> 4, h = bh & 15;
    const size_t hb = (size_t)bh * SEQ * DH;

    // Q fragments: wave's 32 q rows (B-operand: lane q=lm, k = c*32+quad*8+j)
    bf16x8 qf[2][2];
    #pragma unroll
    for (int qt = 0; qt < 2; ++qt)
        #pragma unroll
        for (int c = 0; c < 2; ++c)
            qf[qt][c] = *(const bf16x8*)&qb[hb + (size_t)(q0 + qg * 32 + qt * 16 + lm) * DH + c * 32 + quad * 8];

    // --- staging lane constants (identical to attn9) ---
    const int r0 = (w * 16) + (lane >> 3);
    const int p0 = lane & 7;
    const int gk0 = r0 * 64 + (p0 ^ (r0 & 7)) * 8;          // pre-swizzled global src, n=0
    const int r1 = r0 + 8;
    const int gk1 = r1 * 64 + (p0 ^ (r1 & 7)) * 8;          // n=1
    const unsigned short* kgp = kb + hb;
    const unsigned short* vgp = vt + hb;                     // tiled+swizzled [t][64][32]
    const int gv0 = w * 1024 + lane * 8;
    const int gv1 = gv0 + 512;
    unsigned short* kdst0 = Ks + w * 1024;
    unsigned short* kdst1 = Ks + w * 1024 + 512;
    unsigned short* vdst0 = Vs + w * 1024;
    unsigned short* vdst1 = Vs + w * 1024 + 512;

    // --- frag read offsets (elements, relative to buffer base) ---
    int kfo[2];
    #pragma unroll
    for (int c = 0; c < 2; ++c)
        kfo[c] = (kg * 32 + lm) * 64 + (((c * 4 + quad) ^ (lm & 7)) * 8);
    const int vrow = kg * 2048 + lm * 32;                    // + dt*512 + swizzled slot

    float rs[2] = {0.f, 0.f};
    f32x4 o[2][4];
    #pragma unroll
    for (int qt = 0; qt < 2; ++qt)
        #pragma unroll
        for (int dt = 0; dt < 4; ++dt) o[qt][dt] = (f32x4){0.f, 0.f, 0.f, 0.f};

    // prime: DMA tile 0 into buf 0
    gload_lds16(kgp + gk0, kdst0);
    gload_lds16(kgp + gk1, kdst1);
    gload_lds16(vgp + gv0, vdst0);
    gload_lds16(vgp + gv1, vdst1);

    #pragma unroll 2
    for (int it = 0; it < 32; ++it) {
        const int buf = it & 1;
        __syncthreads();   // drains vmcnt(0): DMA(it) visible; buf^1 free to overwrite
        {
            const size_t nb = (size_t)((it + 1) & 31) * 4096;  // tile base in elements
            const int bo = (buf ^ 1) * 4096;
            gload_lds16(kgp + nb + gk0, kdst0 + bo);
            gload_lds16(kgp + nb + gk1, kdst1 + bo);
            gload_lds16(vgp + nb + gv0, vdst0 + bo);
            gload_lds16(vgp + nb + gv1, vdst1 + bo);
        }
        const unsigned short* Kb = Ks + buf * 4096;
        const unsigned short* Vb = Vs + buf * 4096;

        #pragma unroll
        for (int kt = 0; kt < 2; ++kt) {
            bf16x8 k0 = *(const bf16x8*)&Kb[kfo[0] + kt * 1024];
            bf16x8 k1 = *(const bf16x8*)&Kb[kfo[1] + kt * 1024];
            bf16x4 vb[4];
            #pragma unroll
            for (int dt = 0; dt < 4; ++dt)
                vb[dt] = *(const bf16x4*)&Vb[vrow + dt * 512 + (((kt * 4 + quad) ^ (lm & 7)) << 2)];
            f32x4 s[2];
            #pragma unroll
            for (int qt = 0; qt < 2; ++qt) {
                f32x4 z = (f32x4){0.f, 0.f, 0.f, 0.f};
                z = __builtin_amdgcn_mfma_f32_16x16x32_bf16(k0, qf[qt][0], z, 0, 0, 0);
                s[qt] = __builtin_amdgcn_mfma_f32_16x16x32_bf16(k1, qf[qt][1], z, 0, 0, 0);
            }
            #pragma unroll
            for (int qt = 0; qt < 2; ++qt) {
                unsigned int u[4];
                #pragma unroll
                for (int r = 0; r < 4; ++r) {
                    float p = __builtin_amdgcn_exp2f(s[qt][r]);
                    rs[qt] += p;
                    u[r] = __builtin_bit_cast(unsigned int, p);
                }
                union { unsigned int w2[2]; bf16x4 v; } pk;
                pk.w2[0] = __builtin_amdgcn_perm(u[1], u[0], 0x07060302);
                pk.w2[1] = __builtin_amdgcn_perm(u[3], u[2], 0x07060302);
                // P fragment is already in A-operand layout for K=16 MFMA: row=q=lm,
                // k=quad*4+{0..3}. Accumulate PV directly, no LDS round-trip.
                #pragma unroll
                for (int dt = 0; dt < 4; ++dt)
                    o[qt][dt] = __builtin_amdgcn_mfma_f32_16x16x16bf16_1k(pk.v, vb[dt], o[qt][dt], 0, 0, 0);
            }
        }
    }

    // quad-reduce rs (full row-sum for q=lm in every lane)
    #pragma unroll
    for (int off = 16; off < 64; off <<= 1)
        #pragma unroll
        for (int qt = 0; qt < 2; ++qt) rs[qt] += __shfl_xor(rs[qt], off, 64);

    // ---- merge the 2 k-groups (linear softmax: plain add) ----
    __syncthreads();   // drains last dummy DMA before overlaying smem
    float* oBuf = (float*)smem;                  // [64 q][68] floats = 17408 B (overlays Ks/Vs)
    float* lRed = (float*)(smem + 17408);        // [64]
    if (kg == 1) {
        #pragma unroll
        for (int qt = 0; qt < 2; ++qt)
            #pragma unroll
            for (int dt = 0; dt < 4; ++dt)
                #pragma unroll
                for (int r = 0; r < 4; ++r)
                    oBuf[(qg * 32 + qt * 16 + quad * 4 + r) * 68 + dt * 16 + lm] = o[qt][dt][r];
        if (quad == 0) {
            #pragma unroll
            for (int qt = 0; qt < 2; ++qt) lRed[qg * 32 + qt * 16 + lm] = rs[qt];
        }
    }
    __syncthreads();
    if (kg == 0) {
        #pragma unroll
        for (int qt = 0; qt < 2; ++qt) {
            rs[qt] += lRed[qg * 32 + qt * 16 + lm];
            #pragma unroll
            for (int dt = 0; dt < 4; ++dt)
                #pragma unroll
                for (int r = 0; r < 4; ++r)
                    o[qt][dt][r] += oBuf[(qg * 32 + qt * 16 + quad * 4 + r) * 68 + dt * 16 + lm];
        }
        #pragma unroll
        for (int qt = 0; qt < 2; ++qt)
            #pragma unroll
            for (int r = 0; r < 4; ++r) {
                float inv = 1.0f / __shfl(rs[qt], quad * 4 + r, 64);
                int row = b * SEQ + q0 + qg * 32 + qt * 16 + quad * 4 + r;
                #pragma unroll
                for (int dt = 0; dt < 4; ++dt)
                    attnb[(size_t)row * HID + h * DH + dt * 16 + lm] = f2bf(o[qt][dt][r] * inv);
            }
    }
}

// ========== output GEMM v4 (r10 proven) ==========
__global__ __launch_bounds__(256, 4) void gemm_out(const unsigned short* __restrict__ A,
                                                   const unsigned short* __restrict__ Bt,
                                                   float* __restrict__ C)
{
    __shared__ __align__(16) unsigned short As[64 * 64];    // 8 KB
    __shared__ __align__(16) unsigned short Bs[64 * 64];    // 8 KB
    const int tid = threadIdx.x;
    const int w = tid >> 6, lane = tid & 63;
    const int quad = lane >> 4, lm = lane & 15;
    const int wr = w * 16;                                  // wave rows [wr, wr+16)
    const int bm = blockIdx.y * 64, bn = blockIdx.x * 64;

    const int ga = w * 8 + (lane >> 3);                     // row within 32-row group
    const int gp = ((lane & 7) ^ (lane >> 3)) << 3;         // pre-swizzled source chunk

    int cko[2];
    #pragma unroll
    for (int c = 0; c < 2; ++c)
        cko[c] = (((c * 4 + quad) ^ (lm & 7)) << 3);

    f32x4 acc[4];
    #pragma unroll
    for (int j = 0; j < 4; ++j) acc[j] = (f32x4){0.f, 0.f, 0.f, 0.f};

    for (int k0 = 0; k0 < 1024; k0 += 64) {
        __syncthreads();
        #pragma unroll
        for (int i = 0; i < 2; ++i)
            gload_lds16(&A [(size_t)(bm + i * 32 + ga) * 1024 + k0 + gp], As + i * 2048 + w * 512);
        #pragma unroll
        for (int i = 0; i < 2; ++i)
            gload_lds16(&Bt[(size_t)(bn + i * 32 + ga) * 1024 + k0 + gp], Bs + i * 2048 + w * 512);
        __syncthreads();
        bf16x8 af[2], bfr[4][2];
        #pragma unroll
        for (int c = 0; c < 2; ++c)
            af[c] = *(const bf16x8*)&As[(wr + lm) * 64 + cko[c]];
        #pragma unroll
        for (int nt = 0; nt < 4; ++nt)
            #pragma unroll
            for (int c = 0; c < 2; ++c)
                bfr[nt][c] = *(const bf16x8*)&Bs[(nt * 16 + lm) * 64 + cko[c]];
        #pragma unroll
        for (int nt = 0; nt < 4; ++nt) {
            acc[nt] = __builtin_amdgcn_mfma_f32_16x16x32_bf16(af[0], bfr[nt][0], acc[nt], 0, 0, 0);
            acc[nt] = __builtin_amdgcn_mfma_f32_16x16x32_bf16(af[1], bfr[nt][1], acc[nt], 0, 0, 0);
        }
    }

    #pragma unroll
    for (int nt = 0; nt < 4; ++nt) {
        int col = bn + nt * 16 + lm;
        #pragma unroll
        for (int r = 0; r < 4; ++r) {
            int row = bm + wr + quad * 4 + r;
            C[(size_t)row * 1024 + col] = acc[nt][r];
        }
    }
}

extern "C" void kernel_launch(void* const* d_in, const int* in_sizes, int n_in,
                              void* d_out, int out_size, void* d_ws, size_t ws_size,
                              hipStream_t stream) {
    const float* x     = (const float*)d_in[0];
    const float* rot   = (const float*)d_in[1];
    const float* w_qkv = (const float*)d_in[2];
    const float* w_out = (const float*)d_in[3];
    float* out = (float*)d_out;

    char* ws = (char*)d_ws;
    unsigned short* xb    = (unsigned short*)(ws);                         // 8 MB
    unsigned short* qb    = (unsigned short*)(ws + (size_t)( 8u << 20));   // 8 MB [bh][seq][64]
    unsigned short* kb    = (unsigned short*)(ws + (size_t)(16u << 20));   // 8 MB [bh][seq][64]
    unsigned short* vt    = (unsigned short*)(ws + (size_t)(24u << 20));   // 8 MB [bh][seq/32][64][32] slot-swizzled
    unsigned short* attnb = (unsigned short*)(ws + (size_t)(32u << 20));   // 8 MB
    unsigned short* wqkvT = (unsigned short*)(ws + (size_t)(40u << 20));   // 6 MB
    unsigned short* woutT = (unsigned short*)(ws + (size_t)(46u << 20));   // 2 MB
    float2*         ctab  = (float2*)        (ws + (size_t)(48u << 20));   // 1 MB

    prep<<<3584, 256, 0, stream>>>(x, rot, w_qkv, w_out, xb, ctab, wqkvT, woutT);

    gemm_qkv<<<dim3(24, 32), 256, 0, stream>>>(xb, wqkvT, ctab, qb, kb, vt);

    attn13<<<dim3(32, 32), 256, 0, stream>>>(qb, kb, vt, attnb);

    gemm_out<<<dim3(16, 64), 256, 0, stream>>>(attnb, woutT, out);
}

// Round 15
// 174.317 us; speedup vs baseline: 1.0071x; 1.0071x over previous
//
#include <hip/hip_runtime.h>
#include <math.h>

#define HEADS 16
#define DH    64
#define SEQ   2048
#define HID   1024
#define NROW  4096

typedef __attribute__((ext_vector_type(8))) short bf16x8;
typedef __attribute__((ext_vector_type(4))) short bf16x4;
typedef __attribute__((ext_vector_type(4))) float f32x4;

#define AS1 __attribute__((address_space(1)))
#define AS3 __attribute__((address_space(3)))

// 0.125 * log2(e): folds softmax scale and exp->exp2 into the Q pack.
#define QSCALE 0.18033688011112042f

__device__ __forceinline__ unsigned short f2bf(float x) {
    unsigned int u = __builtin_bit_cast(unsigned int, x);
    u = (u + 0x7FFFu + ((u >> 16) & 1u)) >> 16;
    return (unsigned short)u;
}

__device__ __forceinline__ void gload_lds16(const unsigned short* g, unsigned short* l) {
    __builtin_amdgcn_global_load_lds((AS1 void*)g, (AS3 void*)l, 16, 0, 0);
}

// ================= prep: conv_x + rope_tab + 2x wtrans in ONE launch =================
__device__ void wtrans_body(const float* __restrict__ wsrc, unsigned short* __restrict__ wt,
                            int K, int N, int bx, int by, float (*T)[65])
{
    const int tid = threadIdx.x;
    const int k0 = by * 64, n0 = bx * 64;
    #pragma unroll
    for (int rnd = 0; rnd < 4; ++rnd) {
        int row = (tid >> 4) + rnd * 16;
        int c = (tid & 15) * 4;
        float4 v = *(const float4*)&wsrc[(size_t)(k0 + row) * N + n0 + c];
        T[row][c] = v.x; T[row][c+1] = v.y; T[row][c+2] = v.z; T[row][c+3] = v.w;
    }
    __syncthreads();
    const int sr = tid >> 3, sc = (tid & 7) << 3;
    #pragma unroll
    for (int half = 0; half < 2; ++half) {
        int n = sr + half * 32;
        union { unsigned short u[8]; bf16x8 v; } pk;
        #pragma unroll
        for (int j = 0; j < 8; ++j) pk.u[j] = f2bf(T[sc + j][n]);
        *(bf16x8*)&wt[(size_t)(n0 + n) * K + k0 + sc] = pk.v;
    }
}

__global__ __launch_bounds__(256) void prep(const float* __restrict__ x,
                                            const float* __restrict__ rot,
                                            const float* __restrict__ w_qkv,
                                            const float* __restrict__ w_out,
                                            unsigned short* __restrict__ xb,
                                            float2* __restrict__ ctab,
                                            unsigned short* __restrict__ wqkvT,
                                            unsigned short* __restrict__ woutT)
{
    __shared__ float T[64][65];
    const int bid = blockIdx.x;
    if (bid < 2048) {
        size_t i = ((size_t)bid * 256 + threadIdx.x) * 8;
        float4 a = *(const float4*)&x[i];
        float4 b = *(const float4*)&x[i + 4];
        union { unsigned short u[8]; bf16x8 v; } pk;
        pk.u[0] = f2bf(a.x); pk.u[1] = f2bf(a.y); pk.u[2] = f2bf(a.z); pk.u[3] = f2bf(a.w);
        pk.u[4] = f2bf(b.x); pk.u[5] = f2bf(b.y); pk.u[6] = f2bf(b.z); pk.u[7] = f2bf(b.w);
        *(bf16x8*)&xb[i] = pk.v;
    } else if (bid < 2560) {
        int i = (bid - 2048) * 256 + threadIdx.x;   // SEQ*DH = 131072
        float r = rot[i];
        float s, c;
        __sincosf(r, &s, &c);
        ctab[i] = make_float2(c, s);
    } else if (bid < 3328) {
        int idx = bid - 2560;                       // 48 x 16
        wtrans_body(w_qkv, wqkvT, 1024, 3072, idx % 48, idx / 48, T);
    } else {
        int idx = bid - 3328;                       // 16 x 16
        wtrans_body(w_out, woutT, 1024, 1024, idx % 16, idx / 16, T);
    }
}

// ========== QKV GEMM v6: 128x128 tile, 2x2 wave grid (64x64/wave) — r10 proven ==========
// V written TILED+SWIZZLED: vt[bh][t][d][ks'] with ks' = ((ks>>2) ^ (d&7))<<2.
__global__ __launch_bounds__(256, 3) void gemm_qkv(const unsigned short* __restrict__ A,
                                                   const unsigned short* __restrict__ Bt,
                                                   const float2* __restrict__ ctab,
                                                   unsigned short* __restrict__ qb,
                                                   unsigned short* __restrict__ kb,
                                                   unsigned short* __restrict__ vt)
{
    __shared__ __align__(16) unsigned short As[128 * 64];   // 16 KB, chunk-XOR swizzled
    __shared__ __align__(16) unsigned short Bs[128 * 64];   // 16 KB
    const int tid = threadIdx.x;
    const int w = tid >> 6, lane = tid & 63;
    const int quad = lane >> 4, lm = lane & 15;
    const int wrow = (w >> 1) * 64, wcol = (w & 1) * 64;
    const int bm = blockIdx.y * 128, bn = blockIdx.x * 128;

    // staging constants: each gload line covers 32 rows x 64 cols (8 rows/wave)
    const int ga = w * 8 + (lane >> 3);                     // row within 32-row group
    const int gp = ((lane & 7) ^ (lane >> 3)) << 3;         // pre-swizzled source chunk

    // fragment read chunk offsets for the two K=32 halves
    int cko[2];
    #pragma unroll
    for (int c = 0; c < 2; ++c)
        cko[c] = (((c * 4 + quad) ^ (lm & 7)) << 3);

    f32x4 acc[4][4];
    #pragma unroll
    for (int i = 0; i < 4; ++i)
        #pragma unroll
        for (int j = 0; j < 4; ++j) acc[i][j] = (f32x4){0.f, 0.f, 0.f, 0.f};

    for (int k0 = 0; k0 < 1024; k0 += 64) {
        __syncthreads();
        #pragma unroll
        for (int i = 0; i < 4; ++i)
            gload_lds16(&A [(size_t)(bm + i * 32 + ga) * 1024 + k0 + gp], As + i * 2048 + w * 512);
        #pragma unroll
        for (int i = 0; i < 4; ++i)
            gload_lds16(&Bt[(size_t)(bn + i * 32 + ga) * 1024 + k0 + gp], Bs + i * 2048 + w * 512);
        __syncthreads();
        bf16x8 af[4][2], bfr[4][2];
        #pragma unroll
        for (int mt = 0; mt < 4; ++mt)
            #pragma unroll
            for (int c = 0; c < 2; ++c)
                af[mt][c] = *(const bf16x8*)&As[(wrow + mt * 16 + lm) * 64 + cko[c]];
        #pragma unroll
        for (int nt = 0; nt < 4; ++nt)
            #pragma unroll
            for (int c = 0; c < 2; ++c)
                bfr[nt][c] = *(const bf16x8*)&Bs[(wcol + nt * 16 + lm) * 64 + cko[c]];
        #pragma unroll
        for (int mt = 0; mt < 4; ++mt)
            #pragma unroll
            for (int nt = 0; nt < 4; ++nt) {
                acc[mt][nt] = __builtin_amdgcn_mfma_f32_16x16x32_bf16(af[mt][0], bfr[nt][0], acc[mt][nt], 0, 0, 0);
                acc[mt][nt] = __builtin_amdgcn_mfma_f32_16x16x32_bf16(af[mt][1], bfr[nt][1], acc[mt][nt], 0, 0, 0);
            }
    }

    const int colbase = bn + wcol;         // wave's 64-col slice = one (region, head)
    const int region = colbase >> 10;      // 0=q, 1=k, 2=v
    const int h = (colbase >> 6) & 15;

    if (region == 2) {
        #pragma unroll
        for (int mt = 0; mt < 4; ++mt) {
            int rowb = bm + wrow + mt * 16 + quad * 4;
            int b = rowb >> 11, seq = rowb & (SEQ - 1);
            int t = seq >> 5, ks = seq & 31;            // ks is a multiple of 4
            #pragma unroll
            for (int nt = 0; nt < 4; ++nt) {
                int d = nt * 16 + lm;
                int ksw = (((ks >> 2) ^ (lm & 7)) << 2);   // slot-level XOR swizzle
                ushort4 pk;
                pk.x = f2bf(acc[mt][nt][0]); pk.y = f2bf(acc[mt][nt][1]);
                pk.z = f2bf(acc[mt][nt][2]); pk.w = f2bf(acc[mt][nt][3]);
                *(ushort4*)&vt[(((size_t)(b * HEADS + h) * 64 + t) * 64 + d) * 32 + ksw] = pk;
            }
        }
    } else {
        const float qs = (region == 0) ? QSCALE : 1.0f;
        unsigned short* dst = (region == 0) ? qb : kb;
        #pragma unroll
        for (int mt = 0; mt < 4; ++mt) {
            #pragma unroll
            for (int nt = 0; nt < 2; ++nt) {
                int d = nt * 16 + lm;
                #pragma unroll
                for (int r = 0; r < 4; ++r) {
                    int row = bm + wrow + mt * 16 + quad * 4 + r;
                    int b = row >> 11, seq = row & (SEQ - 1);
                    float2 cs0 = ctab[seq * DH + d];
                    float2 cs1 = ctab[seq * DH + d + 32];
                    float x0 = acc[mt][nt][r];
                    float x1 = acc[mt][nt + 2][r];
                    size_t ob = ((size_t)(b * HEADS + h) * SEQ + seq) * DH;
                    dst[ob + d]      = f2bf((x0 * cs0.x - x1 * cs0.y) * qs);
                    dst[ob + d + 32] = f2bf((x1 * cs1.x + x0 * cs1.y) * qs);
                }
            }
        }
    }
}

// ========== Flash attention v13 (r10 proven: exp2 + scalar rs, exact fp32 denominator) ==========
// r11/r12 lesson (pre-committed): MFMA-rowsum with bf16 P in the denominator fails
// numerics (7e-3 / NaN) — the denominator stays on the exp2 + scalar-add + shfl path.
__global__ __launch_bounds__(256, 4) void attn13(const unsigned short* __restrict__ qb,
                                                 const unsigned short* __restrict__ kb,
                                                 const unsigned short* __restrict__ vt,
                                                 unsigned short* __restrict__ attnb)
{
    __shared__ __align__(16) char smem[32768];
    unsigned short* Ks = (unsigned short*)smem;             // [2 buf][64 kseq][64 d] swizzled rows
    unsigned short* Vs = (unsigned short*)(smem + 16384);   // [2 buf][2 t][64 d][32 ks'] slot-swizzled

    const int tid = threadIdx.x;
    const int w = tid >> 6, lane = tid & 63, quad = lane >> 4, lm = lane & 15;
    const int qg = w >> 1, kg = w & 1;

    // XCD-aware remap: all 32 q-tiles of one bh land on one XCD (linear L = x + 32y).
    // Per-XCD K/V working set = 4 bh x 512 KB = 2 MB < 4 MB L2.
    const int L = blockIdx.x + blockIdx.y * 32;
    const int bh = (L & 7) + 8 * ((L >> 3) & 3);
    const int q0 = (L >> 5) * 64;

    const int b = bh >> 4, h = bh & 15;
    const size_t hb = (size_t)bh * SEQ * DH;

    // Q fragments: wave's 32 q rows (B-operand: lane q=lm, k = c*32+quad*8+j)
    bf16x8 qf[2][2];
    #pragma unroll
    for (int qt = 0; qt < 2; ++qt)
        #pragma unroll
        for (int c = 0; c < 2; ++c)
            qf[qt][c] = *(const bf16x8*)&qb[hb + (size_t)(q0 + qg * 32 + qt * 16 + lm) * DH + c * 32 + quad * 8];

    // --- staging lane constants (identical to attn9) ---
    const int r0 = (w * 16) + (lane >> 3);
    const int p0 = lane & 7;
    const int gk0 = r0 * 64 + (p0 ^ (r0 & 7)) * 8;          // pre-swizzled global src, n=0
    const int r1 = r0 + 8;
    const int gk1 = r1 * 64 + (p0 ^ (r1 & 7)) * 8;          // n=1
    const unsigned short* kgp = kb + hb;
    const unsigned short* vgp = vt + hb;                     // tiled+swizzled [t][64][32]
    const int gv0 = w * 1024 + lane * 8;
    const int gv1 = gv0 + 512;
    unsigned short* kdst0 = Ks + w * 1024;
    unsigned short* kdst1 = Ks + w * 1024 + 512;
    unsigned short* vdst0 = Vs + w * 1024;
    unsigned short* vdst1 = Vs + w * 1024 + 512;

    // --- frag read offsets (elements, relative to buffer base) ---
    int kfo[2];
    #pragma unroll
    for (int c = 0; c < 2; ++c)
        kfo[c] = (kg * 32 + lm) * 64 + (((c * 4 + quad) ^ (lm & 7)) * 8);
    const int vrow = kg * 2048 + lm * 32;                    // + dt*512 + swizzled slot

    float rs[2] = {0.f, 0.f};
    f32x4 o[2][4];
    #pragma unroll
    for (int qt = 0; qt < 2; ++qt)
        #pragma unroll
        for (int dt = 0; dt < 4; ++dt) o[qt][dt] = (f32x4){0.f, 0.f, 0.f, 0.f};

    // prime: DMA tile 0 into buf 0
    gload_lds16(kgp + gk0, kdst0);
    gload_lds16(kgp + gk1, kdst1);
    gload_lds16(vgp + gv0, vdst0);
    gload_lds16(vgp + gv1, vdst1);

    #pragma unroll 2
    for (int it = 0; it < 32; ++it) {
        const int buf = it & 1;
        __syncthreads();   // drains vmcnt(0): DMA(it) visible; buf^1 free to overwrite
        {
            const size_t nb = (size_t)((it + 1) & 31) * 4096;  // tile base in elements
            const int bo = (buf ^ 1) * 4096;
            gload_lds16(kgp + nb + gk0, kdst0 + bo);
            gload_lds16(kgp + nb + gk1, kdst1 + bo);
            gload_lds16(vgp + nb + gv0, vdst0 + bo);
            gload_lds16(vgp + nb + gv1, vdst1 + bo);
        }
        const unsigned short* Kb = Ks + buf * 4096;
        const unsigned short* Vb = Vs + buf * 4096;

        #pragma unroll
        for (int kt = 0; kt < 2; ++kt) {
            bf16x8 k0 = *(const bf16x8*)&Kb[kfo[0] + kt * 1024];
            bf16x8 k1 = *(const bf16x8*)&Kb[kfo[1] + kt * 1024];
            bf16x4 vb[4];
            #pragma unroll
            for (int dt = 0; dt < 4; ++dt)
                vb[dt] = *(const bf16x4*)&Vb[vrow + dt * 512 + (((kt * 4 + quad) ^ (lm & 7)) << 2)];
            f32x4 s[2];
            #pragma unroll
            for (int qt = 0; qt < 2; ++qt) {
                f32x4 z = (f32x4){0.f, 0.f, 0.f, 0.f};
                z = __builtin_amdgcn_mfma_f32_16x16x32_bf16(k0, qf[qt][0], z, 0, 0, 0);
                s[qt] = __builtin_amdgcn_mfma_f32_16x16x32_bf16(k1, qf[qt][1], z, 0, 0, 0);
            }
            #pragma unroll
            for (int qt = 0; qt < 2; ++qt) {
                unsigned int u[4];
                #pragma unroll
                for (int r = 0; r < 4; ++r) {
                    float p = __builtin_amdgcn_exp2f(s[qt][r]);
                    rs[qt] += p;
                    u[r] = __builtin_bit_cast(unsigned int, p);
                }
                union { unsigned int w2[2]; bf16x4 v; } pk;
                pk.w2[0] = __builtin_amdgcn_perm(u[1], u[0], 0x07060302);
                pk.w2[1] = __builtin_amdgcn_perm(u[3], u[2], 0x07060302);
                // P fragment is already in A-operand layout for K=16 MFMA: row=q=lm,
                // k=quad*4+{0..3}. Accumulate PV directly, no LDS round-trip.
                #pragma unroll
                for (int dt = 0; dt < 4; ++dt)
                    o[qt][dt] = __builtin_amdgcn_mfma_f32_16x16x16bf16_1k(pk.v, vb[dt], o[qt][dt], 0, 0, 0);
            }
        }
    }

    // quad-reduce rs (full row-sum for q=lm in every lane)
    #pragma unroll
    for (int off = 16; off < 64; off <<= 1)
        #pragma unroll
        for (int qt = 0; qt < 2; ++qt) rs[qt] += __shfl_xor(rs[qt], off, 64);

    // ---- merge the 2 k-groups (linear softmax: plain add) ----
    __syncthreads();   // drains last dummy DMA before overlaying smem
    float* oBuf = (float*)smem;                  // [64 q][68] floats = 17408 B (overlays Ks/Vs)
    float* lRed = (float*)(smem + 17408);        // [64]
    if (kg == 1) {
        #pragma unroll
        for (int qt = 0; qt < 2; ++qt)
            #pragma unroll
            for (int dt = 0; dt < 4; ++dt)
                #pragma unroll
                for (int r = 0; r < 4; ++r)
                    oBuf[(qg * 32 + qt * 16 + quad * 4 + r) * 68 + dt * 16 + lm] = o[qt][dt][r];
        if (quad == 0) {
            #pragma unroll
            for (int qt = 0; qt < 2; ++qt) lRed[qg * 32 + qt * 16 + lm] = rs[qt];
        }
    }
    __syncthreads();
    if (kg == 0) {
        #pragma unroll
        for (int qt = 0; qt < 2; ++qt) {
            rs[qt] += lRed[qg * 32 + qt * 16 + lm];
            #pragma unroll
            for (int dt = 0; dt < 4; ++dt)
                #pragma unroll
                for (int r = 0; r < 4; ++r)
                    o[qt][dt][r] += oBuf[(qg * 32 + qt * 16 + quad * 4 + r) * 68 + dt * 16 + lm];
        }
        #pragma unroll
        for (int qt = 0; qt < 2; ++qt)
            #pragma unroll
            for (int r = 0; r < 4; ++r) {
                float inv = 1.0f / __shfl(rs[qt], quad * 4 + r, 64);
                int row = b * SEQ + q0 + qg * 32 + qt * 16 + quad * 4 + r;
                #pragma unroll
                for (int dt = 0; dt < 4; ++dt)
                    attnb[(size_t)row * HID + h * DH + dt * 16 + lm] = f2bf(o[qt][dt][r] * inv);
            }
    }
}

// ========== output GEMM v5: 64x64 block, 2x2 wave grid (32x32/wave) — reuse 1.6 -> 2.0 ==========
// r14: apply the r9/r10 reuse lever to gemm_out. Same grid (1024 blocks = 4/CU), same
// 16 KB LDS, same staging/XOR swizzle (fragment rows stay ≡ lm mod 8); only the wave
// decomposition changes: 4x(16x64) -> 2x2 waves of 32x32. Per wave-iter: 8 ds_read_b128
// feed 8 MFMAs (was 10 reads / 8 MFMAs).
__global__ __launch_bounds__(256, 4) void gemm_out(const unsigned short* __restrict__ A,
                                                   const unsigned short* __restrict__ Bt,
                                                   float* __restrict__ C)
{
    __shared__ __align__(16) unsigned short As[64 * 64];    // 8 KB
    __shared__ __align__(16) unsigned short Bs[64 * 64];    // 8 KB
    const int tid = threadIdx.x;
    const int w = tid >> 6, lane = tid & 63;
    const int quad = lane >> 4, lm = lane & 15;
    const int wrow = (w >> 1) * 32, wcol = (w & 1) * 32;    // wave tile: 32x32
    const int bm = blockIdx.y * 64, bn = blockIdx.x * 64;

    const int ga = w * 8 + (lane >> 3);                     // row within 32-row group
    const int gp = ((lane & 7) ^ (lane >> 3)) << 3;         // pre-swizzled source chunk

    int cko[2];
    #pragma unroll
    for (int c = 0; c < 2; ++c)
        cko[c] = (((c * 4 + quad) ^ (lm & 7)) << 3);

    f32x4 acc[2][2];
    #pragma unroll
    for (int i = 0; i < 2; ++i)
        #pragma unroll
        for (int j = 0; j < 2; ++j) acc[i][j] = (f32x4){0.f, 0.f, 0.f, 0.f};

    for (int k0 = 0; k0 < 1024; k0 += 64) {
        __syncthreads();
        #pragma unroll
        for (int i = 0; i < 2; ++i)
            gload_lds16(&A [(size_t)(bm + i * 32 + ga) * 1024 + k0 + gp], As + i * 2048 + w * 512);
        #pragma unroll
        for (int i = 0; i < 2; ++i)
            gload_lds16(&Bt[(size_t)(bn + i * 32 + ga) * 1024 + k0 + gp], Bs + i * 2048 + w * 512);
        __syncthreads();
        bf16x8 af[2][2], bfr[2][2];
        #pragma unroll
        for (int mt = 0; mt < 2; ++mt)
            #pragma unroll
            for (int c = 0; c < 2; ++c)
                af[mt][c] = *(const bf16x8*)&As[(wrow + mt * 16 + lm) * 64 + cko[c]];
        #pragma unroll
        for (int nt = 0; nt < 2; ++nt)
            #pragma unroll
            for (int c = 0; c < 2; ++c)
                bfr[nt][c] = *(const bf16x8*)&Bs[(wcol + nt * 16 + lm) * 64 + cko[c]];
        #pragma unroll
        for (int mt = 0; mt < 2; ++mt)
            #pragma unroll
            for (int nt = 0; nt < 2; ++nt) {
                acc[mt][nt] = __builtin_amdgcn_mfma_f32_16x16x32_bf16(af[mt][0], bfr[nt][0], acc[mt][nt], 0, 0, 0);
                acc[mt][nt] = __builtin_amdgcn_mfma_f32_16x16x32_bf16(af[mt][1], bfr[nt][1], acc[mt][nt], 0, 0, 0);
            }
    }

    #pragma unroll
    for (int mt = 0; mt < 2; ++mt)
        #pragma unroll
        for (int nt = 0; nt < 2; ++nt) {
            int col = bn + wcol + nt * 16 + lm;
            #pragma unroll
            for (int r = 0; r < 4; ++r) {
                int row = bm + wrow + mt * 16 + quad * 4 + r;
                C[(size_t)row * 1024 + col] = acc[mt][nt][r];
            }
        }
}

extern "C" void kernel_launch(void* const* d_in, const int* in_sizes, int n_in,
                              void* d_out, int out_size, void* d_ws, size_t ws_size,
                              hipStream_t stream) {
    const float* x     = (const float*)d_in[0];
    const float* rot   = (const float*)d_in[1];
    const float* w_qkv = (const float*)d_in[2];
    const float* w_out = (const float*)d_in[3];
    float* out = (float*)d_out;

    char* ws = (char*)d_ws;
    unsigned short* xb    = (unsigned short*)(ws);                         // 8 MB
    unsigned short* qb    = (unsigned short*)(ws + (size_t)( 8u << 20));   // 8 MB [bh][seq][64]
    unsigned short* kb    = (unsigned short*)(ws + (size_t)(16u << 20));   // 8 MB [bh][seq][64]
    unsigned short* vt    = (unsigned short*)(ws + (size_t)(24u << 20));   // 8 MB [bh][seq/32][64][32] slot-swizzled
    unsigned short* attnb = (unsigned short*)(ws + (size_t)(32u << 20));   // 8 MB
    unsigned short* wqkvT = (unsigned short*)(ws + (size_t)(40u << 20));   // 6 MB
    unsigned short* woutT = (unsigned short*)(ws + (size_t)(46u << 20));   // 2 MB
    float2*         ctab  = (float2*)        (ws + (size_t)(48u << 20));   // 1 MB

    prep<<<3584, 256, 0, stream>>>(x, rot, w_qkv, w_out, xb, ctab, wqkvT, woutT);

    gemm_qkv<<<dim3(24, 32), 256, 0, stream>>>(xb, wqkvT, ctab, qb, kb, vt);

    attn13<<<dim3(32, 32), 256, 0, stream>>>(qb, kb, vt, attnb);

    gemm_out<<<dim3(16, 64), 256, 0, stream>>>(attnb, woutT, out);
}